// Round 4
// baseline (149.497 us; speedup 1.0000x reference)
//
#include <hip/hip_runtime.h>
#include <stdint.h>

#define BB 16
#define TT 4096
#define DDIM 512
#define KK 128
#define TCB 128            // t-rows per chunk
#define NCB (TT / TCB)     // 32 chunks
#define PI_F 3.14159265358979323846f

typedef unsigned short u16;
typedef __attribute__((ext_vector_type(8))) short short8;
typedef __attribute__((ext_vector_type(4))) float f32x4;

__device__ __forceinline__ uint32_t cvt_bf16_rn(float f) {
  uint32_t u = __float_as_uint(f);
  return (u + 0x7FFFu + ((u >> 16) & 1u)) >> 16;
}
__device__ __forceinline__ void split2(float a, float b, uint32_t& h, uint32_t& l) {
  uint32_t ha = cvt_bf16_rn(a), hb = cvt_bf16_rn(b);
  float ra = a - __uint_as_float(ha << 16);
  float rb = b - __uint_as_float(hb << 16);
  h = ha | (hb << 16);
  l = cvt_bf16_rn(ra) | (cvt_bf16_rn(rb) << 16);
}
__device__ __forceinline__ void split8v(const float4 f0, const float4 f1, uint4& h, uint4& l) {
  split2(f0.x, f0.y, h.x, l.x);
  split2(f0.z, f0.w, h.y, l.y);
  split2(f1.x, f1.y, h.z, l.z);
  split2(f1.z, f1.w, h.w, l.w);
}
__device__ __forceinline__ void gload_lds16(const void* g, void* l) {
  __builtin_amdgcn_global_load_lds(
      (const __attribute__((address_space(1))) void*)g,
      (__attribute__((address_space(3))) void*)l, 16, 0, 0);
}

// ---------------- kernel 0: fused prep (wpack | ct | params) ----------------
// blocks 0..63: pack W into per-d0-tile swizzled bf16 hi/lo images
// blocks 64..79: ct[b] = inclusive cumsum of dt[b]
// block 80: sigma + per-k params
__global__ __launch_bounds__(256) void k_prep(
    const float* __restrict__ W, const float* __restrict__ u_sn,
    const float* __restrict__ s_real_raw, const float* __restrict__ s_imag,
    const float* __restrict__ bias, const float* __restrict__ b_log,
    const float* __restrict__ dt,
    float* __restrict__ params, u16* __restrict__ Wp, float* __restrict__ ct) {
  int gb = blockIdx.x;
  int tid = threadIdx.x;
  if (gb < 64) {
    // ---- wpack: image idx = k*64 + ((dl>>3)^(k&7))*8 + (dl&7)
    int idx = gb * 256 + tid;
    int k = idx >> 7;
    int d = (idx & 127) * 4;
    float4 v = *(const float4*)&W[(size_t)k * DDIM + d];
    uint32_t h0, l0, h1, l1;
    split2(v.x, v.y, h0, l0);
    split2(v.z, v.w, h1, l1);
    int tile = d >> 6, dl = d & 63;
    int slot = (dl >> 3) ^ (k & 7);
    int e = dl & 7;
    size_t base = (size_t)tile * 16384 + k * 64 + slot * 8 + e;
    *(uint32_t*)&Wp[base] = h0;
    *(uint32_t*)&Wp[base + 2] = h1;
    *(uint32_t*)&Wp[base + 8192] = l0;
    *(uint32_t*)&Wp[base + 8192 + 2] = l1;
  } else if (gb < 80) {
    // ---- ct
    __shared__ float sc[256];
    int b = gb - 64;
    const float* row = dt + (size_t)b * TT;
    float* orow = ct + (size_t)b * TT;
    float loc[16];
    float s = 0.f;
    int base = tid * 16;
    for (int i = 0; i < 16; ++i) { s += row[base + i]; loc[i] = s; }
    sc[tid] = s;
    __syncthreads();
    for (int off = 1; off < 256; off <<= 1) {
      float v = (tid >= off) ? sc[tid - off] : 0.f;
      __syncthreads();
      sc[tid] += v;
      __syncthreads();
    }
    float excl = sc[tid] - s;
    for (int i = 0; i < 16; ++i) orow[base + i] = excl + loc[i];
  } else {
    // ---- params
    __shared__ float su[KK];
    __shared__ float sv[DDIM];
    __shared__ float red[4];
    __shared__ float s_sig;
    if (tid < KK) su[tid] = u_sn[tid];
    __syncthreads();
    for (int rep = 0; rep < 2; ++rep) {
      int d = tid + rep * 256;
      float acc = 0.f;
      for (int k = 0; k < KK; ++k) acc += W[k * DDIM + d] * su[k];
      sv[d] = acc;
    }
    __syncthreads();
    float nn = 0.f;
    for (int rep = 0; rep < 2; ++rep) { float v = sv[tid + rep * 256]; nn += v * v; }
    for (int off = 32; off > 0; off >>= 1) nn += __shfl_down(nn, off, 64);
    if ((tid & 63) == 0) red[tid >> 6] = nn;
    __syncthreads();
    float vn2 = red[0] + red[1] + red[2] + red[3];
    __syncthreads();
    float vinv = 1.f / (sqrtf(vn2) + 1e-6f);
    for (int rep = 0; rep < 2; ++rep) sv[tid + rep * 256] *= vinv;
    __syncthreads();
    float wv = 0.f;
    if (tid < KK) {
      const float* wrow = W + (size_t)tid * DDIM;
      for (int d = 0; d < DDIM; ++d) wv += wrow[d] * sv[d];
    }
    float q = wv * wv;
    for (int off = 32; off > 0; off >>= 1) q += __shfl_down(q, off, 64);
    if ((tid & 63) == 0) red[tid >> 6] = q;
    __syncthreads();
    if (tid == 0) {
      float wn2 = red[0] + red[1] + red[2] + red[3];
      s_sig = wn2 / (sqrtf(wn2) + 1e-6f);
    }
    __syncthreads();
    if (tid < KK) {
      float inv_sigma = 1.f / s_sig;
      float sr = s_real_raw[tid];
      float alpha = ((sr > 20.f) ? sr : log1pf(expf(sr))) + 1e-6f;
      float om = fminf(fmaxf(s_imag[tid], -PI_F), PI_F);
      float bg = expf(b_log[tid]);
      params[tid] = alpha;
      params[KK + tid] = om;
      params[2 * KK + tid] = bg * inv_sigma;
      params[3 * KK + tid] = bg * bias[tid];
    }
  }
}

// ---------------- kernel 1: fused MFMA GEMM + scan + lookback + finalize ----------------
// D[t][k]: A = x-tile (bf16 hi/lo in LDS), B = W-tile (pre-packed, global_load_lds).
// C layout: row = t = (l>>4)*4+reg, col = k = l&15.
__global__ __launch_bounds__(512, 4) void k_gemm_scan(
    const float* __restrict__ x, const u16* __restrict__ Wp,
    const float* __restrict__ dt, const float* __restrict__ ct,
    const float* __restrict__ params, float* __restrict__ out,
    float* __restrict__ csum_re, float* __restrict__ csum_im,
    int* __restrict__ flags) {
  __shared__ __align__(16) u16 smem[32768];   // 64 KB
  u16* xhi = smem;            // [128][64]
  u16* xlo = smem + 8192;
  u16* whi = smem + 16384;    // [128][64]
  u16* wlo = smem + 24576;

  const int chunk = blockIdx.x, b = blockIdx.y;
  const int tid = threadIdx.x;
  const int wv = tid >> 6, l = tid & 63;
  const int lm = l & 15, lg = l >> 4;
  const int kw = wv & 1, tw = wv >> 1;
  const int t0 = chunk * TCB;

  const int xr = tid >> 2, xq = (tid & 3) * 16;
  const size_t xbase = ((size_t)b * TT + t0 + xr) * DDIM + xq;
  const char* wsrc0 = (const char*)Wp + (size_t)wv * 1024 + (size_t)l * 16;
  char* wdst0 = (char*)whi + wv * 1024;
  const int xs0 = ((xq >> 3) ^ (xr & 7)) * 8;
  const int xs1 = (((xq >> 3) + 1) ^ (xr & 7)) * 8;

  f32x4 acc[2][4];
#pragma unroll
  for (int m = 0; m < 2; ++m)
#pragma unroll
    for (int n = 0; n < 4; ++n) acc[m][n] = (f32x4)(0.0f);

  for (int d0 = 0; d0 < DDIM; d0 += 64) {
    const char* wsg = wsrc0 + (size_t)(d0 >> 6) * 32768;
#pragma unroll
    for (int r = 0; r < 4; ++r)
      gload_lds16(wsg + r * 8192, wdst0 + r * 8192);
    const float* xp = x + xbase + d0;
    float4 f0 = *(const float4*)(xp + 0);
    float4 f1 = *(const float4*)(xp + 4);
    float4 f2 = *(const float4*)(xp + 8);
    float4 f3 = *(const float4*)(xp + 12);
    uint4 h0, lo0, h1, lo1;
    split8v(f0, f1, h0, lo0);
    split8v(f2, f3, h1, lo1);
    *(uint4*)&xhi[xr * 64 + xs0] = h0;
    *(uint4*)&xhi[xr * 64 + xs1] = h1;
    *(uint4*)&xlo[xr * 64 + xs0] = lo0;
    *(uint4*)&xlo[xr * 64 + xs1] = lo1;
    __syncthreads();
#pragma unroll
    for (int ks = 0; ks < 2; ++ks) {
      short8 fa_h[2], fa_l[2], fb_h[4], fb_l[4];
#pragma unroll
      for (int m = 0; m < 2; ++m) {
        int row = tw * 32 + m * 16 + lm;
        int sw = ((ks * 4 + lg) ^ (row & 7)) * 8;
        fa_h[m] = *(const short8*)&xhi[row * 64 + sw];
        fa_l[m] = *(const short8*)&xlo[row * 64 + sw];
      }
#pragma unroll
      for (int n = 0; n < 4; ++n) {
        int row = kw * 64 + n * 16 + lm;
        int sw = ((ks * 4 + lg) ^ (row & 7)) * 8;
        fb_h[n] = *(const short8*)&whi[row * 64 + sw];
        fb_l[n] = *(const short8*)&wlo[row * 64 + sw];
      }
#pragma unroll
      for (int m = 0; m < 2; ++m)
#pragma unroll
        for (int n = 0; n < 4; ++n) {
          acc[m][n] = __builtin_amdgcn_mfma_f32_16x16x32_bf16(fa_h[m], fb_h[n], acc[m][n], 0, 0, 0);
          acc[m][n] = __builtin_amdgcn_mfma_f32_16x16x32_bf16(fa_l[m], fb_h[n], acc[m][n], 0, 0, 0);
          acc[m][n] = __builtin_amdgcn_mfma_f32_16x16x32_bf16(fa_h[m], fb_l[n], acc[m][n], 0, 0, 0);
        }
    }
    __syncthreads();
  }

  // ---- params per n (k = kw*64 + n*16 + lm), dt/ct per (m,r)
  float pal[4], pom[4], pc1[4], pc2[4];
#pragma unroll
  for (int n = 0; n < 4; ++n) {
    int k = kw * 64 + n * 16 + lm;
    pal[n] = params[k];
    pom[n] = params[KK + k];
    pc1[n] = params[2 * KK + k];
    pc2[n] = params[3 * KK + k];
  }
  float dtv[2][4], ctv[2][4];
#pragma unroll
  for (int m = 0; m < 2; ++m)
#pragma unroll
    for (int r = 0; r < 4; ++r) {
      int t = t0 + tw * 32 + m * 16 + lg * 4 + r;
      dtv[m][r] = dt[(size_t)b * TT + t];
      ctv[m][r] = ct[(size_t)b * TT + t];
    }
  // ---- transform g -> w (complex contribution)
  float vre[2][4][4], vim[2][4][4];
#pragma unroll
  for (int m = 0; m < 2; ++m)
#pragma unroll
    for (int n = 0; n < 4; ++n)
#pragma unroll
      for (int r = 0; r < 4; ++r) {
        float g = acc[m][n][r];
        float a = pal[n] * dtv[m][r];
        float omr = a * (1.f - a * (0.5f - a * (1.f / 6.f)));  // 1 - exp(-a)
        float itv = omr * (pc1[n] * g + pc2[n]);
        float e = __expf(pal[n] * ctv[m][r]);
        float sn, cs;
        __sincosf(pom[n] * ctv[m][r], &sn, &cs);
        vre[m][n][r] = itv * e * cs;
        vim[m][n][r] = -(itv * e) * sn;
      }
  // ---- scan over t within wave: serial r, 2-step lg prefix, chain m
  float carR[4], carI[4];
#pragma unroll
  for (int n = 0; n < 4; ++n) {
    float cr = 0.f, ci = 0.f;
#pragma unroll
    for (int m = 0; m < 2; ++m) {
      vre[m][n][1] += vre[m][n][0];
      vre[m][n][2] += vre[m][n][1];
      vre[m][n][3] += vre[m][n][2];
      vim[m][n][1] += vim[m][n][0];
      vim[m][n][2] += vim[m][n][1];
      vim[m][n][3] += vim[m][n][2];
      float ar = vre[m][n][3], ai = vim[m][n][3];
      float tr = ar, ti = ai;
      float ur = __shfl_up(ar, 16, 64);
      float ui = __shfl_up(ai, 16, 64);
      if (lg >= 1) { ar += ur; ai += ui; }
      ur = __shfl_up(ar, 32, 64);
      ui = __shfl_up(ai, 32, 64);
      if (lg >= 2) { ar += ur; ai += ui; }
      float exr = ar - tr + cr;
      float exi = ai - ti + ci;
#pragma unroll
      for (int r = 0; r < 4; ++r) { vre[m][n][r] += exr; vim[m][n][r] += exi; }
      cr += __shfl(ar, 48 + lm, 64);
      ci += __shfl(ai, 48 + lm, 64);
    }
    carR[n] = cr; carI[n] = ci;
  }
  // ---- cross-wave (tw) carry via LDS
  float* totr = (float*)smem;         // [4][128]
  float* toti = (float*)smem + 4 * KK;
  if (lg == 0)
#pragma unroll
    for (int n = 0; n < 4; ++n) {
      totr[tw * KK + kw * 64 + n * 16 + lm] = carR[n];
      toti[tw * KK + kw * 64 + n * 16 + lm] = carI[n];
    }
  __syncthreads();
  float crR[4] = {0.f, 0.f, 0.f, 0.f}, crI[4] = {0.f, 0.f, 0.f, 0.f};
  for (int t2 = 0; t2 < tw; ++t2)
#pragma unroll
    for (int n = 0; n < 4; ++n) {
      crR[n] += totr[t2 * KK + kw * 64 + n * 16 + lm];
      crI[n] += toti[t2 * KK + kw * 64 + n * 16 + lm];
    }
  // ---- publish chunk aggregate (agent-scope), then release flag
  if (tw == 3 && lg == 0)
#pragma unroll
    for (int n = 0; n < 4; ++n) {
      int k = kw * 64 + n * 16 + lm;
      size_t idx = ((size_t)b * NCB + chunk) * KK + k;
      __hip_atomic_store(&csum_re[idx], crR[n] + carR[n], __ATOMIC_RELAXED, __HIP_MEMORY_SCOPE_AGENT);
      __hip_atomic_store(&csum_im[idx], crI[n] + carI[n], __ATOMIC_RELAXED, __HIP_MEMORY_SCOPE_AGENT);
    }
  __syncthreads();
  if (tid == 0)
    __hip_atomic_store(&flags[b * NCB + chunk], 1, __ATOMIC_RELEASE, __HIP_MEMORY_SCOPE_AGENT);

  // ---- decoupled look-back: sum predecessor aggregates in fixed order
  float* pre = (float*)smem + 2048;   // [256] floats; dead LDS region
  if (chunk > 0) {
    if (tid < 64) {
      for (int c = tid; c < chunk; c += 64)
        while (__hip_atomic_load(&flags[b * NCB + c], __ATOMIC_ACQUIRE, __HIP_MEMORY_SCOPE_AGENT) == 0)
          __builtin_amdgcn_s_sleep(2);
    }
    __syncthreads();
    if (tid < 256) {
      int v = tid & 127;
      float* srcp = (tid < 128) ? csum_re : csum_im;
      float a = 0.f;
      for (int c = 0; c < chunk; ++c)
        a += __hip_atomic_load(&srcp[((size_t)b * NCB + c) * KK + v], __ATOMIC_RELAXED, __HIP_MEMORY_SCOPE_AGENT);
      pre[tid] = a;
    }
  } else {
    if (tid < 256) pre[tid] = 0.f;
  }
  __syncthreads();

  // ---- add prefix, rotate by e^{-(alpha - i omega) ct}, emit C and S
#pragma unroll
  for (int m = 0; m < 2; ++m)
#pragma unroll
    for (int r = 0; r < 4; ++r) {
      size_t rowb = ((size_t)b * TT + t0 + tw * 32 + m * 16 + lg * 4 + r) * (2 * KK);
      float ctv_ = ctv[m][r];
#pragma unroll
      for (int n = 0; n < 4; ++n) {
        int k = kw * 64 + n * 16 + lm;
        float Sre = vre[m][n][r] + crR[n] + pre[k];
        float Sim = vim[m][n][r] + crI[n] + pre[KK + k];
        float dec = __expf(-pal[n] * ctv_);
        float sn, cs;
        __sincosf(pom[n] * ctv_, &sn, &cs);
        float Rw = dec * (cs * Sre - sn * Sim);
        float Iw = dec * (cs * Sim + sn * Sre);
        out[rowb + k] = Rw - Iw;        // C
        out[rowb + KK + k] = Rw + Iw;   // S
      }
    }
}

extern "C" void kernel_launch(void* const* d_in, const int* in_sizes, int n_in,
                              void* d_out, int out_size, void* d_ws, size_t ws_size,
                              hipStream_t stream) {
  const float* x    = (const float*)d_in[0];
  const float* dt   = (const float*)d_in[1];
  const float* srr  = (const float*)d_in[2];
  const float* si   = (const float*)d_in[3];
  const float* W    = (const float*)d_in[4];
  const float* bias = (const float*)d_in[5];
  const float* blog = (const float*)d_in[6];
  const float* usn  = (const float*)d_in[7];
  float* out = (float*)d_out;
  float* ws = (float*)d_ws;

  float* params  = ws;                          // 512 f
  float* ct      = ws + 4 * KK;                 // 65536 f
  float* csum_re = ct + (size_t)BB * TT;        // 65536 f
  float* csum_im = csum_re + (size_t)BB * NCB * KK;
  u16*   Wp      = (u16*)(csum_im + (size_t)BB * NCB * KK);  // 131072 u16
  int*   flags   = (int*)(Wp + 131072);         // 512 ints

  hipMemsetAsync(flags, 0, BB * NCB * sizeof(int), stream);
  k_prep<<<81, 256, 0, stream>>>(W, usn, srr, si, bias, blog, dt, params, Wp, ct);
  k_gemm_scan<<<dim3(NCB, BB), 512, 0, stream>>>(x, Wp, dt, ct, params, out,
                                                 csum_re, csum_im, flags);
}